// Round 15
// baseline (202.639 us; speedup 1.0000x reference)
//
#include <hip/hip_runtime.h>

#define DM 1024
#define NH 16
#define HD 64
#define FD 16
#define NF 153
#define FPAD 160
#define WIN 64
#define TSEQ 2048
#define ROWS 4096
#define KSPLIT 32
#define LDKV 1280
#define RS2 0.70710678118654752f

typedef unsigned short u16;
typedef __attribute__((ext_vector_type(8))) short bf16x8;
typedef __attribute__((ext_vector_type(8))) unsigned short u16x8;
typedef __attribute__((ext_vector_type(4))) unsigned short u16x4;
typedef __attribute__((ext_vector_type(4))) float f32x4;

#define GLB_AS __attribute__((address_space(1)))
#define LDS_AS __attribute__((address_space(3)))

static __device__ __forceinline__ void gload_lds16(const void* g, void* l){
  __builtin_amdgcn_global_load_lds((const GLB_AS void*)g, (LDS_AS void*)l, 16, 0, 0);
}

static __device__ __forceinline__ float bf2f(u16 u){
  unsigned v = ((unsigned)u) << 16;
  return __builtin_bit_cast(float, v);
}
static __device__ __forceinline__ u16 f2bf(float f){
  unsigned u = __builtin_bit_cast(unsigned, f);
  u += 0x7FFFu + ((u >> 16) & 1u);
  return (u16)(u >> 16);
}

// ---------------- prep: rmsnorm + enc cast + weight packing + composed K-feature ----------------
static __device__ __forceinline__ void tr_tile(const float* __restrict__ in,
    u16* __restrict__ out, int K, int N, int n0, int k0, float* t, int tid){
  int tx = tid & 31, ty = tid >> 5;
  #pragma unroll
  for (int i=0;i<4;i++) t[(ty + i*8)*33 + tx] = in[(size_t)(k0 + ty + i*8)*N + n0 + tx];
  __syncthreads();
  #pragma unroll
  for (int i=0;i<4;i++) out[(size_t)(n0 + ty + i*8)*K + k0 + tx] = f2bf(t[tx*33 + ty + i*8]);
}

__global__ __launch_bounds__(256) void k_prep(const float* __restrict__ x,
    const float* __restrict__ enc, const float* __restrict__ w,
    const float* __restrict__ Wq, const float* __restrict__ Wwin,
    const float* __restrict__ Wkv, const float* __restrict__ Wout,
    const float* __restrict__ Wqf, const float* __restrict__ Wkf,
    u16* __restrict__ xn, u16* __restrict__ encb,
    u16* __restrict__ WqwT, u16* __restrict__ WkvT2, u16* __restrict__ WoutT,
    u16* __restrict__ WqfT){
  __shared__ float t[32*33];
  __shared__ float wkf[1024];
  int bx = blockIdx.x, tid = threadIdx.x;
  if (bx < ROWS){
    int row = bx;
    const float4* xr = (const float4*)(x + (size_t)row*DM);
    float4 a = xr[tid];
    float ss = a.x*a.x + a.y*a.y + a.z*a.z + a.w*a.w;
    #pragma unroll
    for (int m=1;m<64;m<<=1) ss += __shfl_xor(ss, m);
    __shared__ float red[4];
    if ((tid&63)==0) red[tid>>6] = ss;
    __syncthreads();
    float tot = red[0]+red[1]+red[2]+red[3];
    float rs = rsqrtf(tot*(1.0f/DM) + 1e-6f);
    float4 wv = ((const float4*)w)[tid];
    u16x4 o;
    o[0]=f2bf(a.x*rs*wv.x); o[1]=f2bf(a.y*rs*wv.y);
    o[2]=f2bf(a.z*rs*wv.z); o[3]=f2bf(a.w*rs*wv.w);
    ((u16x4*)(xn + (size_t)row*DM))[tid] = o;
  } else if (bx < 2*ROWS){
    int row = bx - ROWS;
    float4 a = ((const float4*)(enc + (size_t)row*DM))[tid];
    u16x4 o;
    o[0]=f2bf(a.x); o[1]=f2bf(a.y); o[2]=f2bf(a.z); o[3]=f2bf(a.w);
    ((u16x4*)(encb + (size_t)row*DM))[tid] = o;
  } else {
    int b = bx - 2*ROWS;
    if (b < 1024){
      tr_tile(Wq, WqwT, 1024, 1024, (b&31)*32, (b>>5)*32, t, tid);
    } else if (b < 3072){
      int r = b-1024;
      tr_tile(Wwin, WqwT + (size_t)1024*1024, 1024, 2048, (r&63)*32, (r>>6)*32, t, tid);
    } else if (b < 4096){
      int r = b-3072;   // v-part: WkvT2 rows 0..1023 = Wkv cols 1024..2047 transposed
      tr_tile(Wkv + 1024, WkvT2, 1024, 2048, (r&31)*32, (r>>5)*32, t, tid);
    } else if (b < 6144){
      int r = b-4096;
      tr_tile(Wout, WoutT, 2048, 1024, (r&31)*32, (r>>5)*32, t, tid);
    } else if (b == 6144){
      for (int i=tid;i<1024;i+=256) WqfT[i] = f2bf(Wqf[(i&63)*16 + (i>>6)]);
    } else {
      // composed K-feature: CmpT[h*16+f][din] = sum_d Wkv[din][h*64+d] * Wkf[d][f]
      int h = b - 6145;
      for (int i=tid;i<1024;i+=256) wkf[i] = Wkf[i];
      __syncthreads();
      int f = tid&15;
      for (int din = tid>>4; din < 1024; din += 16){
        const float* wr = Wkv + (size_t)din*2048 + h*64;
        float acc = 0.f;
        #pragma unroll
        for (int d=0;d<64;d++) acc += wr[d]*wkf[d*16 + f];
        WkvT2[(size_t)(1024 + h*16 + f)*1024 + din] = f2bf(acc);
      }
    }
  }
}

// ---------------- batched pipelined GEMM: 512 threads, 8 waves, wave tile 64x32 ----------------
// Default block->XCD mapping (R12 measured: chunked swizzle DOUBLES fetch here).
template<int EPI>
__global__ __launch_bounds__(512) void k_gemm(
    const u16* __restrict__ A0, const u16* __restrict__ B0, u16* __restrict__ C0, int ldc0,
    const u16* __restrict__ A1, const u16* __restrict__ B1, u16* __restrict__ C1, int ldc1,
    int split, int K, float* __restrict__ Cf, const float* __restrict__ resid){
  __shared__ u16 As0[128*64];
  __shared__ u16 Bs0[128*64];
  __shared__ u16 As1[128*64];
  __shared__ u16 Bs1[128*64];
  int by = blockIdx.y;
  const u16 *A, *Bt; u16* C; int ldc;
  if (by < split){ A=A0; Bt=B0; C=C0; ldc=ldc0; }
  else { by -= split; A=A1; Bt=B1; C=C1; ldc=ldc1; }
  int row0 = blockIdx.x*128, col0 = by*128;
  int tid = threadIdx.x, lane = tid&63, wid = tid>>6;
  int wm = wid>>2, wn = wid&3;
  int srow = lane>>3;
  int scb  = ((lane&7)*16) ^ (srow<<4);
  f32x4 acc[4][2] = {};

  auto STAGE = [&](u16* Asb, u16* Bsb, int k0){
    #pragma unroll
    for (int i=0;i<2;i++){
      int chunk = wid*2 + i;
      int r = chunk*8 + srow;
      gload_lds16((const char*)(A  + (size_t)(row0+r)*K + k0) + scb, (char*)Asb + chunk*1024);
      gload_lds16((const char*)(Bt + (size_t)(col0+r)*K + k0) + scb, (char*)Bsb + chunk*1024);
    }
  };
  auto COMPUTE = [&](const u16* Asb, const u16* Bsb){
    #pragma unroll
    for (int kk=0;kk<64;kk+=32){
      int bc = 2*(kk + ((lane>>4)<<3));
      bf16x8 af[4], bfm[2];
      #pragma unroll
      for (int m=0;m<4;m++){
        int r = wm*64 + m*16 + (lane&15);
        af[m]  = *(const bf16x8*)((const char*)Asb + r*128 + (bc ^ ((r&7)<<4)));
      }
      #pragma unroll
      for (int n=0;n<2;n++){
        int r = wn*32 + n*16 + (lane&15);
        bfm[n] = *(const bf16x8*)((const char*)Bsb + r*128 + (bc ^ ((r&7)<<4)));
      }
      #pragma unroll
      for (int m=0;m<4;m++)
        #pragma unroll
        for (int n=0;n<2;n++)
          acc[m][n] = __builtin_amdgcn_mfma_f32_16x16x32_bf16(af[m], bfm[n], acc[m][n], 0,0,0);
    }
  };

  int nt = K >> 6;
  STAGE(As0, Bs0, 0);
  for (int t=0; t<nt-2; t+=2){
    STAGE(As1, Bs1, (t+1)*64);
    asm volatile("s_waitcnt vmcnt(4)" ::: "memory");
    __builtin_amdgcn_s_barrier();
    COMPUTE(As0, Bs0);
    __builtin_amdgcn_s_barrier();
    STAGE(As0, Bs0, (t+2)*64);
    asm volatile("s_waitcnt vmcnt(4)" ::: "memory");
    __builtin_amdgcn_s_barrier();
    COMPUTE(As1, Bs1);
    __builtin_amdgcn_s_barrier();
  }
  STAGE(As1, Bs1, (nt-1)*64);
  asm volatile("s_waitcnt vmcnt(4)" ::: "memory");
  __builtin_amdgcn_s_barrier();
  COMPUTE(As0, Bs0);
  asm volatile("s_waitcnt vmcnt(0)" ::: "memory");
  __builtin_amdgcn_s_barrier();
  COMPUTE(As1, Bs1);

  int rl = (lane>>4)<<2;
  #pragma unroll
  for (int m=0;m<4;m++){
    #pragma unroll
    for (int n=0;n<2;n++){
      int gc = col0 + wn*32 + n*16 + (lane&15);
      #pragma unroll
      for (int r=0;r<4;r++){
        size_t gi = (size_t)(row0 + wm*64 + m*16 + rl + r)*ldc + gc;
        if constexpr (EPI) Cf[gi] = acc[m][n][r] + resid[gi];
        else               C[gi]  = f2bf(acc[m][n][r]);
      }
    }
  }
}

// ---------------- Wout GEMM: 128x64 tiles, 512 thr / 8 waves, 48KB LDS ----------------
template<int EPI>
__global__ __launch_bounds__(512) void k_gemmN64(const u16* __restrict__ A,
    const u16* __restrict__ Bt, float* __restrict__ Cf,
    const float* __restrict__ resid, int ldc, int K){
  __shared__ u16 As0[128*64];
  __shared__ u16 Bs0[64*64];
  __shared__ u16 As1[128*64];
  __shared__ u16 Bs1[64*64];
  int row0 = blockIdx.x*128, col0 = blockIdx.y*64;
  int tid = threadIdx.x, lane = tid&63, wid = tid>>6;
  int wm = wid>>1, wn = wid&1;
  int srow = lane>>3;
  int scb  = ((lane&7)*16) ^ (srow<<4);
  f32x4 acc[2][2] = {};

  auto STAGE = [&](u16* Asb, u16* Bsb, int k0){
    #pragma unroll
    for (int j=0;j<2;j++){
      int c = wid*2 + j;
      int r = c*8 + srow;
      gload_lds16((const char*)(A + (size_t)(row0+r)*K + k0) + scb, (char*)Asb + c*1024);
    }
    {
      int c = wid;
      int r = c*8 + srow;
      gload_lds16((const char*)(Bt + (size_t)(col0+r)*K + k0) + scb, (char*)Bsb + c*1024);
    }
  };
  auto COMPUTE = [&](const u16* Asb, const u16* Bsb){
    #pragma unroll
    for (int kk=0;kk<64;kk+=32){
      int bc = 2*(kk + ((lane>>4)<<3));
      bf16x8 af[2], bfm[2];
      #pragma unroll
      for (int m=0;m<2;m++){
        int r = wm*32 + m*16 + (lane&15);
        af[m]  = *(const bf16x8*)((const char*)Asb + r*128 + (bc ^ ((r&7)<<4)));
      }
      #pragma unroll
      for (int n=0;n<2;n++){
        int r = wn*32 + n*16 + (lane&15);
        bfm[n] = *(const bf16x8*)((const char*)Bsb + r*128 + (bc ^ ((r&7)<<4)));
      }
      #pragma unroll
      for (int m=0;m<2;m++)
        #pragma unroll
        for (int n=0;n<2;n++)
          acc[m][n] = __builtin_amdgcn_mfma_f32_16x16x32_bf16(af[m], bfm[n], acc[m][n], 0,0,0);
    }
  };

  int nt = K >> 6;
  STAGE(As0, Bs0, 0);
  for (int t=0; t<nt-2; t+=2){
    STAGE(As1, Bs1, (t+1)*64);
    asm volatile("s_waitcnt vmcnt(3)" ::: "memory");
    __builtin_amdgcn_s_barrier();
    COMPUTE(As0, Bs0);
    __builtin_amdgcn_s_barrier();
    STAGE(As0, Bs0, (t+2)*64);
    asm volatile("s_waitcnt vmcnt(3)" ::: "memory");
    __builtin_amdgcn_s_barrier();
    COMPUTE(As1, Bs1);
    __builtin_amdgcn_s_barrier();
  }
  STAGE(As1, Bs1, (nt-1)*64);
  asm volatile("s_waitcnt vmcnt(3)" ::: "memory");
  __builtin_amdgcn_s_barrier();
  COMPUTE(As0, Bs0);
  asm volatile("s_waitcnt vmcnt(0)" ::: "memory");
  __builtin_amdgcn_s_barrier();
  COMPUTE(As1, Bs1);

  int rl = (lane>>4)<<2;
  #pragma unroll
  for (int m=0;m<2;m++){
    #pragma unroll
    for (int n=0;n<2;n++){
      int gc = col0 + wn*32 + n*16 + (lane&15);
      #pragma unroll
      for (int r=0;r<4;r++){
        size_t gi = (size_t)(row0 + wm*32 + m*16 + rl + r)*ldc + gc;
        if constexpr (EPI) Cf[gi] = acc[m][n][r] + resid[gi];
        else               ((u16*)Cf)[gi] = f2bf(acc[m][n][r]);
      }
    }
  }
}

// ---------------- kv_state: kf precomputed in kvb -> single-barrier structure ----------------
__global__ __launch_bounds__(256) void k_kvstate(const u16* __restrict__ kvb,
    u16* __restrict__ part){
  const int P = 72;
  __shared__ u16 ph[160*P];
  __shared__ u16 vt[80*P];
  int bh = blockIdx.x, b = bh>>4, h = bh&15;
  int ks = blockIdx.y;
  int tid = threadIdx.x, lane = tid&63, w = tid>>6;
  int s0 = ks*64;
  // vt: const rows (64=ones for k_state, 65..79 zero) + staged v columns
  for (int i=tid; i<16*P; i+=256){
    int r = 64 + i/P, c = i - (i/P)*P;
    vt[r*P + c] = (r==64) ? (u16)0x3F80 : (u16)0;
  }
  for (int s = w; s < 64; s += 4)
    vt[lane*P + s] = kvb[(size_t)(b*TSEQ + s0 + s)*LDKV + h*HD + lane];
  // kf load + triu expansion -> ph
  {
    int r = tid>>2, jq = tid&3;
    const u16* kfp = kvb + (size_t)(b*TSEQ + s0 + r)*LDKV + 1024 + h*16;
    u16x8 va = *(const u16x8*)kfp;
    u16x8 vb = *(const u16x8*)(kfp + 8);
    float f[16];
    #pragma unroll
    for (int j=0;j<8;j++){ f[j] = bf2f(va[j]); f[8+j] = bf2f(vb[j]); }
    if ((0&3)==jq) ph[0*P + r] = 0x3F80;
    #pragma unroll
    for (int q=0;q<16;q++) if (((1+q)&3)==jq) ph[(1+q)*P + r] = f2bf(f[q]);
    int pos = 17;
    #pragma unroll
    for (int i=0;i<16;i++)
      #pragma unroll
      for (int j=i;j<16;j++){
        if ((pos&3)==jq) ph[pos*P + r] = f2bf(f[i]*f[j]*((i==j)?0.5f:RS2));
        pos++;
      }
    #pragma unroll
    for (int z=153;z<160;z++) if ((z&3)==jq) ph[z*P + r] = 0;
  }
  __syncthreads();
  f32x4 acc[5][3] = {};
  #pragma unroll
  for (int kk=0;kk<2;kk++){
    int lk = kk*32 + ((lane>>4)<<3);
    bf16x8 bfr[3];
    #pragma unroll
    for (int nn=0;nn<3;nn++){
      int ncol = (nn<2) ? (w*2+nn) : (8+(w&1));
      bfr[nn] = *(const bf16x8*)(ph + (ncol*16 + (lane&15))*P + lk);
    }
    #pragma unroll
    for (int m=0;m<5;m++){
      bf16x8 av = *(const bf16x8*)(vt + (m*16 + (lane&15))*P + lk);
      #pragma unroll
      for (int nn=0;nn<3;nn++)
        acc[m][nn] = __builtin_amdgcn_mfma_f32_16x16x32_bf16(av, bfr[nn], acc[m][nn], 0,0,0);
    }
  }
  int rl = (lane>>4)<<2;
  u16* pp = part + ((size_t)ks*32 + bh)*80*160;
  #pragma unroll
  for (int m=0;m<5;m++){
    #pragma unroll
    for (int nn=0;nn<3;nn++){
      int ncol = (nn<2) ? (w*2+nn) : (8+(w&1));
      if (nn==2 && w>=2) continue;
      int fcol = ncol*16 + (lane&15);
      #pragma unroll
      for (int r=0;r<4;r++)
        pp[(size_t)(m*16 + rl + r)*160 + fcol] = f2bf(acc[m][nn][r]);
    }
  }
}

// ---------------- reduce split-K bf16 partials -> kvsT bf16 [bh][80][160] ----------------
__global__ __launch_bounds__(256) void k_kvreduce(const u16* __restrict__ part,
    u16* __restrict__ kvsT){
  int i = blockIdx.x*256 + threadIdx.x;
  float s = 0.f;
  #pragma unroll
  for (int c=0;c<KSPLIT;c++) s += bf2f(part[(size_t)c*409600 + i]);
  kvsT[i] = f2bf(s);
}

// ---------------- linear attention, 51.2KB LDS -> 3 blocks/CU ----------------
__global__ __launch_bounds__(256) void k_linattn(const u16* __restrict__ qwin,
    const u16* __restrict__ WqfT, const u16* __restrict__ kvsT, u16* __restrict__ comb){
  const int LS = 168;
  __shared__ u16 As[64*LS];
  __shared__ u16 Bs[80*LS];
  __shared__ float fL[64*16];
  int bh = blockIdx.x, b = bh>>4, h = bh&15;
  int t0 = blockIdx.y*64;
  int tid = threadIdx.x, lane = tid&63, wid = tid>>6;
  for (int i=tid*8; i<80*FPAD; i+=2048){
    int r = i/FPAD, ff = i - r*FPAD;
    *(bf16x8*)(Bs + r*LS + ff) = *(const bf16x8*)(kvsT + (size_t)bh*80*FPAD + i);
  }
  {
    f32x4 fa = {};
    const u16* qrow = qwin + (size_t)(b*TSEQ + t0 + wid*16 + (lane&15))*3072 + h*HD;
    const u16* wrow = WqfT + (lane&15)*64;
    #pragma unroll
    for (int kk=0;kk<2;kk++){
      int ko = kk*32 + ((lane>>4)<<3);
      bf16x8 av = *(const bf16x8*)(qrow + ko);
      bf16x8 bv = *(const bf16x8*)(wrow + ko);
      fa = __builtin_amdgcn_mfma_f32_16x16x32_bf16(av, bv, fa, 0,0,0);
    }
    int rl = (lane>>4)<<2;
    #pragma unroll
    for (int r=0;r<4;r++) fL[(wid*16 + rl + r)*16 + (lane&15)] = fa[r];
  }
  __syncthreads();
  {
    int r = tid>>2, jq = tid&3;
    float4 v0 = *(const float4*)(fL + r*16 + 0);
    float4 v1 = *(const float4*)(fL + r*16 + 4);
    float4 v2 = *(const float4*)(fL + r*16 + 8);
    float4 v3 = *(const float4*)(fL + r*16 + 12);
    float f[16] = {v0.x,v0.y,v0.z,v0.w, v1.x,v1.y,v1.z,v1.w,
                   v2.x,v2.y,v2.z,v2.w, v3.x,v3.y,v3.z,v3.w};
    if ((0&3)==jq) As[r*LS + 0] = 0x3F80;
    #pragma unroll
    for (int q=0;q<16;q++) if (((1+q)&3)==jq) As[r*LS + 1+q] = f2bf(f[q]);
    int pos = 17;
    #pragma unroll
    for (int i=0;i<16;i++)
      #pragma unroll
      for (int j=i;j<16;j++){
        if ((pos&3)==jq) As[r*LS + pos] = f2bf(f[i]*f[j]*((i==j)?0.5f:RS2));
        pos++;
      }
    #pragma unroll
    for (int z=153;z<160;z++) if ((z&3)==jq) As[r*LS + z] = 0;
  }
  __syncthreads();
  f32x4 acc[5] = {};
  __builtin_amdgcn_s_setprio(1);
  #pragma unroll
  for (int ks=0;ks<5;ks++){
    int lk = ks*32 + ((lane>>4)<<3);
    bf16x8 a = *(const bf16x8*)(As + (wid*16 + (lane&15))*LS + lk);
    #pragma unroll
    for (int n=0;n<5;n++){
      bf16x8 bb = *(const bf16x8*)(Bs + (n*16 + (lane&15))*LS + lk);
      acc[n] = __builtin_amdgcn_mfma_f32_16x16x32_bf16(a, bb, acc[n], 0,0,0);
    }
  }
  __builtin_amdgcn_s_setprio(0);
  int rl = (lane>>4)<<2;
  #pragma unroll
  for (int r=0;r<4;r++){
    float nrm = __shfl(acc[4][r], lane & 48) + 1e-6f;
    float inv = 1.0f / nrm;
    int t = t0 + wid*16 + rl + r;
    #pragma unroll
    for (int n=0;n<4;n++){
      comb[(size_t)(b*TSEQ + t)*2048 + h*64 + n*16 + (lane&15)] = f2bf(acc[n][r]*inv);
    }
  }
}

// ---------------- sliding-window attention, 53.0KB LDS -> 3 blocks/CU ----------------
__global__ __launch_bounds__(256) void k_window(const u16* __restrict__ qwin,
    u16* __restrict__ comb){
  const int LQ = 72, LV = 136;
  __shared__ u16 k_s [128*LQ];
  __shared__ u16 vT  [64*LV];
  __shared__ u16 p_s [64*LV];
  int bh = blockIdx.x, b = bh>>4, h = bh&15;
  int t0 = blockIdx.y*64;
  int tid = threadIdx.x, lane = tid&63, wid = tid>>6;
  int j0 = t0 - 64;
  bf16x8 zv = {0,0,0,0,0,0,0,0};
  for (int cc=tid; cc<1024; cc+=256){
    int r = cc>>3, c8 = cc&7;
    int j = j0 + r;
    bf16x8 kv8 = (j>=0) ? *(const bf16x8*)(qwin + (size_t)(b*TSEQ + j)*3072 + 1024 + h*HD + c8*8) : zv;
    *(bf16x8*)(k_s + r*LQ + c8*8) = kv8;
    bf16x8 vv8 = (j>=0) ? *(const bf16x8*)(qwin + (size_t)(b*TSEQ + j)*3072 + 2048 + h*HD + c8*8) : zv;
    int cs = r ^ (c8<<3);
    #pragma unroll
    for (int e=0;e<8;e++) vT[(c8*8+e)*LV + cs] = (u16)vv8[e];
  }
  __syncthreads();
  f32x4 sa[8] = {};
  {
    const u16* qrow = qwin + (size_t)(b*TSEQ + t0 + wid*16 + (lane&15))*3072 + h*HD;
    __builtin_amdgcn_s_setprio(1);
    #pragma unroll
    for (int kk=0;kk<64;kk+=32){
      int lk = kk + ((lane>>4)<<3);
      bf16x8 a = *(const bf16x8*)(qrow + lk);
      #pragma unroll
      for (int n=0;n<8;n++){
        bf16x8 bb = *(const bf16x8*)(k_s + (n*16 + (lane&15))*LQ + lk);
        sa[n] = __builtin_amdgcn_mfma_f32_16x16x32_bf16(a, bb, sa[n], 0,0,0);
      }
    }
    __builtin_amdgcn_s_setprio(0);
  }
  int rl = (lane>>4)<<2;
  float pr[8][4];
  #pragma unroll
  for (int r=0;r<4;r++){
    int ig = t0 + wid*16 + rl + r;
    float mx = -1e30f;
    float sv[8];
    #pragma unroll
    for (int n=0;n<8;n++){
      int jg = j0 + n*16 + (lane&15);
      float s = sa[n][r]*0.125f;
      bool ok = (jg>=0) && (jg<=ig) && (jg>=ig-WIN);
      s = ok ? s : -1e30f;
      sv[n]=s; mx = fmaxf(mx, s);
    }
    #pragma unroll
    for (int m=1;m<16;m<<=1) mx = fmaxf(mx, __shfl_xor(mx, m));
    float sum = 0.f;
    #pragma unroll
    for (int n=0;n<8;n++){ float e = __expf(sv[n]-mx); sv[n]=e; sum += e; }
    #pragma unroll
    for (int m=1;m<16;m<<=1) sum += __shfl_xor(sum, m);
    float inv = 1.0f/sum;
    #pragma unroll
    for (int n=0;n<8;n++) pr[n][r] = sv[n]*inv;
  }
  #pragma unroll
  for (int n=0;n<8;n++)
    #pragma unroll
    for (int r=0;r<4;r++)
      p_s[(wid*16 + rl + r)*LV + n*16 + (lane&15)] = f2bf(pr[n][r]);
  __syncthreads();
  f32x4 oa[4] = {};
  __builtin_amdgcn_s_setprio(1);
  #pragma unroll
  for (int ks=0;ks<4;ks++){
    int lk = ks*32 + ((lane>>4)<<3);
    bf16x8 a = *(const bf16x8*)(p_s + (wid*16 + (lane&15))*LV + lk);
    #pragma unroll
    for (int n=0;n<4;n++){
      int d = n*16 + (lane&15);
      bf16x8 bb = *(const bf16x8*)(vT + d*LV + (lk ^ (((d>>3)&7)<<3)));
      oa[n] = __builtin_amdgcn_mfma_f32_16x16x32_bf16(a, bb, oa[n], 0,0,0);
    }
  }
  __builtin_amdgcn_s_setprio(0);
  #pragma unroll
  for (int n=0;n<4;n++)
    #pragma unroll
    for (int r=0;r<4;r++)
      comb[(size_t)(b*TSEQ + t0 + wid*16 + rl + r)*2048 + 1024 + h*HD + n*16 + (lane&15)]
        = f2bf(oa[n][r]);
}

extern "C" void kernel_launch(void* const* d_in, const int* in_sizes, int n_in,
                              void* d_out, int out_size, void* d_ws, size_t ws_size,
                              hipStream_t stream){
  (void)in_sizes; (void)n_in; (void)out_size; (void)ws_size;
  const float* x    = (const float*)d_in[0];
  const float* enc  = (const float*)d_in[1];
  const float* nw   = (const float*)d_in[2];
  const float* Wq   = (const float*)d_in[3];
  const float* Wkv  = (const float*)d_in[4];
  const float* Wqf  = (const float*)d_in[5];
  const float* Wkf  = (const float*)d_in[6];
  const float* Wwin = (const float*)d_in[7];
  const float* Wout = (const float*)d_in[8];
  float* out = (float*)d_out;

  char* p = (char*)d_ws;
  auto alloc = [&](size_t bytes)->char*{
    char* r = p; p += (bytes + 255) & ~(size_t)255; return r;
  };
  u16*   xn    = (u16*)  alloc((size_t)ROWS*DM*2);
  u16*   encb  = (u16*)  alloc((size_t)ROWS*DM*2);
  u16*   WqwT  = (u16*)  alloc((size_t)3072*DM*2);   // rows 0..1023 Wq^T, 1024..3071 Wwin^T
  u16*   WkvT2 = (u16*)  alloc((size_t)LDKV*DM*2);   // rows 0..1023 v-proj^T, 1024..1279 CmpT
  u16*   WoutT = (u16*)  alloc((size_t)DM*2048*2);
  u16*   WqfT  = (u16*)  alloc((size_t)FD*HD*2);
  u16*   qwin  = (u16*)  alloc((size_t)ROWS*3072*2); // [q | k_win | v_win], ld 3072
  u16*   kvb   = (u16*)  alloc((size_t)ROWS*LDKV*2); // [v | kf], ld 1280
  u16*   kvsT  = (u16*)  alloc((size_t)32*80*FPAD*2);
  u16*   comb  = (u16*)  alloc((size_t)ROWS*2048*2);
  u16*   part  = (u16*)  alloc((size_t)KSPLIT*32*80*FPAD*2);  // fresh (no alias): cache-pathology probe

  k_prep<<<2*ROWS + 6161, 256, 0, stream>>>(x, enc, nw, Wq, Wwin, Wkv, Wout, Wqf, Wkf,
                                            xn, encb, WqwT, WkvT2, WoutT, WqfT);

  k_gemm<0><<<dim3(ROWS/128, 34), 512, 0, stream>>>(
      xn, WqwT, qwin, 3072,  encb, WkvT2, kvb, LDKV,  24, DM, nullptr, nullptr);

  k_kvstate<<<dim3(32, KSPLIT), 256, 0, stream>>>(kvb, part);
  k_kvreduce<<<1600, 256, 0, stream>>>(part, kvsT);

  k_linattn<<<dim3(32, TSEQ/64), 256, 0, stream>>>(qwin, WqfT, kvsT, comb);
  k_window <<<dim3(32, TSEQ/64), 256, 0, stream>>>(qwin, comb);

  k_gemmN64<1><<<dim3(ROWS/128, 16), 512, 0, stream>>>(
      comb, WoutT, out, x, DM, 2048);
}

// Round 16
// 149.483 us; speedup vs baseline: 1.3556x; 1.3556x over previous
//
#include <hip/hip_runtime.h>

#define DM 1024
#define NH 16
#define HD 64
#define FD 16
#define NF 153
#define FPAD 160
#define WIN 64
#define TSEQ 2048
#define ROWS 4096
#define KSPLIT 32
#define LDKV 1280
#define RS2 0.70710678118654752f

typedef unsigned short u16;
typedef __attribute__((ext_vector_type(8))) short bf16x8;
typedef __attribute__((ext_vector_type(8))) unsigned short u16x8;
typedef __attribute__((ext_vector_type(4))) unsigned short u16x4;
typedef __attribute__((ext_vector_type(4))) float f32x4;

#define GLB_AS __attribute__((address_space(1)))
#define LDS_AS __attribute__((address_space(3)))

static __device__ __forceinline__ void gload_lds16(const void* g, void* l){
  __builtin_amdgcn_global_load_lds((const GLB_AS void*)g, (LDS_AS void*)l, 16, 0, 0);
}

static __device__ __forceinline__ float bf2f(u16 u){
  unsigned v = ((unsigned)u) << 16;
  return __builtin_bit_cast(float, v);
}
static __device__ __forceinline__ u16 f2bf(float f){
  unsigned u = __builtin_bit_cast(unsigned, f);
  u += 0x7FFFu + ((u >> 16) & 1u);
  return (u16)(u >> 16);
}

// ---------------- prep: rmsnorm + enc cast + weight packing + composed K-feature ----------------
static __device__ __forceinline__ void tr_tile(const float* __restrict__ in,
    u16* __restrict__ out, int K, int N, int n0, int k0, float* t, int tid){
  int tx = tid & 31, ty = tid >> 5;
  #pragma unroll
  for (int i=0;i<4;i++) t[(ty + i*8)*33 + tx] = in[(size_t)(k0 + ty + i*8)*N + n0 + tx];
  __syncthreads();
  #pragma unroll
  for (int i=0;i<4;i++) out[(size_t)(n0 + ty + i*8)*K + k0 + tx] = f2bf(t[tx*33 + ty + i*8]);
}

__global__ __launch_bounds__(256) void k_prep(const float* __restrict__ x,
    const float* __restrict__ enc, const float* __restrict__ w,
    const float* __restrict__ Wq, const float* __restrict__ Wwin,
    const float* __restrict__ Wkv, const float* __restrict__ Wout,
    const float* __restrict__ Wqf, const float* __restrict__ Wkf,
    u16* __restrict__ xn, u16* __restrict__ encb,
    u16* __restrict__ WqwT, u16* __restrict__ WkvT2, u16* __restrict__ WoutT,
    u16* __restrict__ WqfT){
  __shared__ float t[32*33];
  __shared__ float wkf[1024];
  __shared__ float wkv[1024];
  int bx = blockIdx.x, tid = threadIdx.x;
  if (bx < ROWS){
    int row = bx;
    const float4* xr = (const float4*)(x + (size_t)row*DM);
    float4 a = xr[tid];
    float ss = a.x*a.x + a.y*a.y + a.z*a.z + a.w*a.w;
    #pragma unroll
    for (int m=1;m<64;m<<=1) ss += __shfl_xor(ss, m);
    __shared__ float red[4];
    if ((tid&63)==0) red[tid>>6] = ss;
    __syncthreads();
    float tot = red[0]+red[1]+red[2]+red[3];
    float rs = rsqrtf(tot*(1.0f/DM) + 1e-6f);
    float4 wv = ((const float4*)w)[tid];
    u16x4 o;
    o[0]=f2bf(a.x*rs*wv.x); o[1]=f2bf(a.y*rs*wv.y);
    o[2]=f2bf(a.z*rs*wv.z); o[3]=f2bf(a.w*rs*wv.w);
    ((u16x4*)(xn + (size_t)row*DM))[tid] = o;
  } else if (bx < 2*ROWS){
    int row = bx - ROWS;
    float4 a = ((const float4*)(enc + (size_t)row*DM))[tid];
    u16x4 o;
    o[0]=f2bf(a.x); o[1]=f2bf(a.y); o[2]=f2bf(a.z); o[3]=f2bf(a.w);
    ((u16x4*)(encb + (size_t)row*DM))[tid] = o;
  } else {
    int b = bx - 2*ROWS;
    if (b < 1024){
      tr_tile(Wq, WqwT, 1024, 1024, (b&31)*32, (b>>5)*32, t, tid);
    } else if (b < 3072){
      int r = b-1024;
      tr_tile(Wwin, WqwT + (size_t)1024*1024, 1024, 2048, (r&63)*32, (r>>6)*32, t, tid);
    } else if (b < 4096){
      int r = b-3072;   // v-part: WkvT2 rows 0..1023 = Wkv cols 1024..2047 transposed
      tr_tile(Wkv + 1024, WkvT2, 1024, 2048, (r&31)*32, (r>>5)*32, t, tid);
    } else if (b < 6144){
      int r = b-4096;
      tr_tile(Wout, WoutT, 2048, 1024, (r&31)*32, (r>>5)*32, t, tid);
    } else if (b == 6144){
      for (int i=tid;i<1024;i+=256) WqfT[i] = f2bf(Wqf[(i&63)*16 + (i>>6)]);
    } else {
      // composed K-feature, PARALLEL over 1024 blocks (R15 lesson: 16-block
      // serial-scalar tail cost ~80us). Block = (h, din-chunk of 16).
      int idx = b - 6145;
      int h = idx >> 6, dc = idx & 63;
      for (int i=tid;i<1024;i+=256) wkf[i] = Wkf[i];
      {
        int rr = tid>>6, cc = tid&63;
        #pragma unroll
        for (int r2=0;r2<4;r2++)
          wkv[(rr + r2*4)*64 + cc] = Wkv[(size_t)(dc*16 + rr + r2*4)*2048 + h*64 + cc];
      }
      __syncthreads();
      int f = tid&15, dl = tid>>4;
      float acc = 0.f;
      #pragma unroll
      for (int d=0;d<64;d++) acc += wkv[dl*64 + d]*wkf[d*16 + f];
      WkvT2[(size_t)(1024 + h*16 + f)*1024 + dc*16 + dl] = f2bf(acc);
    }
  }
}

// ---------------- batched pipelined GEMM: 512 threads, 8 waves, wave tile 64x32 ----------------
// Default block->XCD mapping (R12 measured: chunked swizzle DOUBLES fetch here).
template<int EPI>
__global__ __launch_bounds__(512) void k_gemm(
    const u16* __restrict__ A0, const u16* __restrict__ B0, u16* __restrict__ C0, int ldc0,
    const u16* __restrict__ A1, const u16* __restrict__ B1, u16* __restrict__ C1, int ldc1,
    int split, int K, float* __restrict__ Cf, const float* __restrict__ resid){
  __shared__ u16 As0[128*64];
  __shared__ u16 Bs0[128*64];
  __shared__ u16 As1[128*64];
  __shared__ u16 Bs1[128*64];
  int by = blockIdx.y;
  const u16 *A, *Bt; u16* C; int ldc;
  if (by < split){ A=A0; Bt=B0; C=C0; ldc=ldc0; }
  else { by -= split; A=A1; Bt=B1; C=C1; ldc=ldc1; }
  int row0 = blockIdx.x*128, col0 = by*128;
  int tid = threadIdx.x, lane = tid&63, wid = tid>>6;
  int wm = wid>>2, wn = wid&3;
  int srow = lane>>3;
  int scb  = ((lane&7)*16) ^ (srow<<4);
  f32x4 acc[4][2] = {};

  auto STAGE = [&](u16* Asb, u16* Bsb, int k0){
    #pragma unroll
    for (int i=0;i<2;i++){
      int chunk = wid*2 + i;
      int r = chunk*8 + srow;
      gload_lds16((const char*)(A  + (size_t)(row0+r)*K + k0) + scb, (char*)Asb + chunk*1024);
      gload_lds16((const char*)(Bt + (size_t)(col0+r)*K + k0) + scb, (char*)Bsb + chunk*1024);
    }
  };
  auto COMPUTE = [&](const u16* Asb, const u16* Bsb){
    #pragma unroll
    for (int kk=0;kk<64;kk+=32){
      int bc = 2*(kk + ((lane>>4)<<3));
      bf16x8 af[4], bfm[2];
      #pragma unroll
      for (int m=0;m<4;m++){
        int r = wm*64 + m*16 + (lane&15);
        af[m]  = *(const bf16x8*)((const char*)Asb + r*128 + (bc ^ ((r&7)<<4)));
      }
      #pragma unroll
      for (int n=0;n<2;n++){
        int r = wn*32 + n*16 + (lane&15);
        bfm[n] = *(const bf16x8*)((const char*)Bsb + r*128 + (bc ^ ((r&7)<<4)));
      }
      #pragma unroll
      for (int m=0;m<4;m++)
        #pragma unroll
        for (int n=0;n<2;n++)
          acc[m][n] = __builtin_amdgcn_mfma_f32_16x16x32_bf16(af[m], bfm[n], acc[m][n], 0,0,0);
    }
  };

  int nt = K >> 6;
  STAGE(As0, Bs0, 0);
  for (int t=0; t<nt-2; t+=2){
    STAGE(As1, Bs1, (t+1)*64);
    asm volatile("s_waitcnt vmcnt(4)" ::: "memory");
    __builtin_amdgcn_s_barrier();
    COMPUTE(As0, Bs0);
    __builtin_amdgcn_s_barrier();
    STAGE(As0, Bs0, (t+2)*64);
    asm volatile("s_waitcnt vmcnt(4)" ::: "memory");
    __builtin_amdgcn_s_barrier();
    COMPUTE(As1, Bs1);
    __builtin_amdgcn_s_barrier();
  }
  STAGE(As1, Bs1, (nt-1)*64);
  asm volatile("s_waitcnt vmcnt(4)" ::: "memory");
  __builtin_amdgcn_s_barrier();
  COMPUTE(As0, Bs0);
  asm volatile("s_waitcnt vmcnt(0)" ::: "memory");
  __builtin_amdgcn_s_barrier();
  COMPUTE(As1, Bs1);

  int rl = (lane>>4)<<2;
  #pragma unroll
  for (int m=0;m<4;m++){
    #pragma unroll
    for (int n=0;n<2;n++){
      int gc = col0 + wn*32 + n*16 + (lane&15);
      #pragma unroll
      for (int r=0;r<4;r++){
        size_t gi = (size_t)(row0 + wm*64 + m*16 + rl + r)*ldc + gc;
        if constexpr (EPI) Cf[gi] = acc[m][n][r] + resid[gi];
        else               C[gi]  = f2bf(acc[m][n][r]);
      }
    }
  }
}

// ---------------- Wout GEMM: 128x64 tiles, 512 thr / 8 waves, 48KB LDS ----------------
template<int EPI>
__global__ __launch_bounds__(512) void k_gemmN64(const u16* __restrict__ A,
    const u16* __restrict__ Bt, float* __restrict__ Cf,
    const float* __restrict__ resid, int ldc, int K){
  __shared__ u16 As0[128*64];
  __shared__ u16 Bs0[64*64];
  __shared__ u16 As1[128*64];
  __shared__ u16 Bs1[64*64];
  int row0 = blockIdx.x*128, col0 = blockIdx.y*64;
  int tid = threadIdx.x, lane = tid&63, wid = tid>>6;
  int wm = wid>>1, wn = wid&1;
  int srow = lane>>3;
  int scb  = ((lane&7)*16) ^ (srow<<4);
  f32x4 acc[2][2] = {};

  auto STAGE = [&](u16* Asb, u16* Bsb, int k0){
    #pragma unroll
    for (int j=0;j<2;j++){
      int c = wid*2 + j;
      int r = c*8 + srow;
      gload_lds16((const char*)(A + (size_t)(row0+r)*K + k0) + scb, (char*)Asb + c*1024);
    }
    {
      int c = wid;
      int r = c*8 + srow;
      gload_lds16((const char*)(Bt + (size_t)(col0+r)*K + k0) + scb, (char*)Bsb + c*1024);
    }
  };
  auto COMPUTE = [&](const u16* Asb, const u16* Bsb){
    #pragma unroll
    for (int kk=0;kk<64;kk+=32){
      int bc = 2*(kk + ((lane>>4)<<3));
      bf16x8 af[2], bfm[2];
      #pragma unroll
      for (int m=0;m<2;m++){
        int r = wm*32 + m*16 + (lane&15);
        af[m]  = *(const bf16x8*)((const char*)Asb + r*128 + (bc ^ ((r&7)<<4)));
      }
      #pragma unroll
      for (int n=0;n<2;n++){
        int r = wn*32 + n*16 + (lane&15);
        bfm[n] = *(const bf16x8*)((const char*)Bsb + r*128 + (bc ^ ((r&7)<<4)));
      }
      #pragma unroll
      for (int m=0;m<2;m++)
        #pragma unroll
        for (int n=0;n<2;n++)
          acc[m][n] = __builtin_amdgcn_mfma_f32_16x16x32_bf16(af[m], bfm[n], acc[m][n], 0,0,0);
    }
  };

  int nt = K >> 6;
  STAGE(As0, Bs0, 0);
  for (int t=0; t<nt-2; t+=2){
    STAGE(As1, Bs1, (t+1)*64);
    asm volatile("s_waitcnt vmcnt(3)" ::: "memory");
    __builtin_amdgcn_s_barrier();
    COMPUTE(As0, Bs0);
    __builtin_amdgcn_s_barrier();
    STAGE(As0, Bs0, (t+2)*64);
    asm volatile("s_waitcnt vmcnt(3)" ::: "memory");
    __builtin_amdgcn_s_barrier();
    COMPUTE(As1, Bs1);
    __builtin_amdgcn_s_barrier();
  }
  STAGE(As1, Bs1, (nt-1)*64);
  asm volatile("s_waitcnt vmcnt(3)" ::: "memory");
  __builtin_amdgcn_s_barrier();
  COMPUTE(As0, Bs0);
  asm volatile("s_waitcnt vmcnt(0)" ::: "memory");
  __builtin_amdgcn_s_barrier();
  COMPUTE(As1, Bs1);

  int rl = (lane>>4)<<2;
  #pragma unroll
  for (int m=0;m<2;m++){
    #pragma unroll
    for (int n=0;n<2;n++){
      int gc = col0 + wn*32 + n*16 + (lane&15);
      #pragma unroll
      for (int r=0;r<4;r++){
        size_t gi = (size_t)(row0 + wm*32 + m*16 + rl + r)*ldc + gc;
        if constexpr (EPI) Cf[gi] = acc[m][n][r] + resid[gi];
        else               ((u16*)Cf)[gi] = f2bf(acc[m][n][r]);
      }
    }
  }
}

// ---------------- kv_state: kf precomputed in kvb -> single-barrier structure ----------------
__global__ __launch_bounds__(256) void k_kvstate(const u16* __restrict__ kvb,
    u16* __restrict__ part){
  const int P = 72;
  __shared__ u16 ph[160*P];
  __shared__ u16 vt[80*P];
  int bh = blockIdx.x, b = bh>>4, h = bh&15;
  int ks = blockIdx.y;
  int tid = threadIdx.x, lane = tid&63, w = tid>>6;
  int s0 = ks*64;
  for (int i=tid; i<16*P; i+=256){
    int r = 64 + i/P, c = i - (i/P)*P;
    vt[r*P + c] = (r==64) ? (u16)0x3F80 : (u16)0;
  }
  for (int s = w; s < 64; s += 4)
    vt[lane*P + s] = kvb[(size_t)(b*TSEQ + s0 + s)*LDKV + h*HD + lane];
  {
    int r = tid>>2, jq = tid&3;
    const u16* kfp = kvb + (size_t)(b*TSEQ + s0 + r)*LDKV + 1024 + h*16;
    u16x8 va = *(const u16x8*)kfp;
    u16x8 vb = *(const u16x8*)(kfp + 8);
    float f[16];
    #pragma unroll
    for (int j=0;j<8;j++){ f[j] = bf2f(va[j]); f[8+j] = bf2f(vb[j]); }
    if ((0&3)==jq) ph[0*P + r] = 0x3F80;
    #pragma unroll
    for (int q=0;q<16;q++) if (((1+q)&3)==jq) ph[(1+q)*P + r] = f2bf(f[q]);
    int pos = 17;
    #pragma unroll
    for (int i=0;i<16;i++)
      #pragma unroll
      for (int j=i;j<16;j++){
        if ((pos&3)==jq) ph[pos*P + r] = f2bf(f[i]*f[j]*((i==j)?0.5f:RS2));
        pos++;
      }
    #pragma unroll
    for (int z=153;z<160;z++) if ((z&3)==jq) ph[z*P + r] = 0;
  }
  __syncthreads();
  f32x4 acc[5][3] = {};
  #pragma unroll
  for (int kk=0;kk<2;kk++){
    int lk = kk*32 + ((lane>>4)<<3);
    bf16x8 bfr[3];
    #pragma unroll
    for (int nn=0;nn<3;nn++){
      int ncol = (nn<2) ? (w*2+nn) : (8+(w&1));
      bfr[nn] = *(const bf16x8*)(ph + (ncol*16 + (lane&15))*P + lk);
    }
    #pragma unroll
    for (int m=0;m<5;m++){
      bf16x8 av = *(const bf16x8*)(vt + (m*16 + (lane&15))*P + lk);
      #pragma unroll
      for (int nn=0;nn<3;nn++)
        acc[m][nn] = __builtin_amdgcn_mfma_f32_16x16x32_bf16(av, bfr[nn], acc[m][nn], 0,0,0);
    }
  }
  int rl = (lane>>4)<<2;
  u16* pp = part + ((size_t)ks*32 + bh)*80*160;
  #pragma unroll
  for (int m=0;m<5;m++){
    #pragma unroll
    for (int nn=0;nn<3;nn++){
      int ncol = (nn<2) ? (w*2+nn) : (8+(w&1));
      if (nn==2 && w>=2) continue;
      int fcol = ncol*16 + (lane&15);
      #pragma unroll
      for (int r=0;r<4;r++)
        pp[(size_t)(m*16 + rl + r)*160 + fcol] = f2bf(acc[m][nn][r]);
    }
  }
}

// ---------------- reduce split-K bf16 partials -> kvsT bf16 [bh][80][160] ----------------
__global__ __launch_bounds__(256) void k_kvreduce(const u16* __restrict__ part,
    u16* __restrict__ kvsT){
  int i = blockIdx.x*256 + threadIdx.x;
  float s = 0.f;
  #pragma unroll
  for (int c=0;c<KSPLIT;c++) s += bf2f(part[(size_t)c*409600 + i]);
  kvsT[i] = f2bf(s);
}

// ---------------- linear attention, 51.2KB LDS -> 3 blocks/CU ----------------
__global__ __launch_bounds__(256) void k_linattn(const u16* __restrict__ qwin,
    const u16* __restrict__ WqfT, const u16* __restrict__ kvsT, u16* __restrict__ comb){
  const int LS = 168;
  __shared__ u16 As[64*LS];
  __shared__ u16 Bs[80*LS];
  __shared__ float fL[64*16];
  int bh = blockIdx.x, b = bh>>4, h = bh&15;
  int t0 = blockIdx.y*64;
  int tid = threadIdx.x, lane = tid&63, wid = tid>>6;
  for (int i=tid*8; i<80*FPAD; i+=2048){
    int r = i/FPAD, ff = i - r*FPAD;
    *(bf16x8*)(Bs + r*LS + ff) = *(const bf16x8*)(kvsT + (size_t)bh*80*FPAD + i);
  }
  {
    f32x4 fa = {};
    const u16* qrow = qwin + (size_t)(b*TSEQ + t0 + wid*16 + (lane&15))*3072 + h*HD;
    const u16* wrow = WqfT + (lane&15)*64;
    #pragma unroll
    for (int kk=0;kk<2;kk++){
      int ko = kk*32 + ((lane>>4)<<3);
      bf16x8 av = *(const bf16x8*)(qrow + ko);
      bf16x8 bv = *(const bf16x8*)(wrow + ko);
      fa = __builtin_amdgcn_mfma_f32_16x16x32_bf16(av, bv, fa, 0,0,0);
    }
    int rl = (lane>>4)<<2;
    #pragma unroll
    for (int r=0;r<4;r++) fL[(wid*16 + rl + r)*16 + (lane&15)] = fa[r];
  }
  __syncthreads();
  {
    int r = tid>>2, jq = tid&3;
    float4 v0 = *(const float4*)(fL + r*16 + 0);
    float4 v1 = *(const float4*)(fL + r*16 + 4);
    float4 v2 = *(const float4*)(fL + r*16 + 8);
    float4 v3 = *(const float4*)(fL + r*16 + 12);
    float f[16] = {v0.x,v0.y,v0.z,v0.w, v1.x,v1.y,v1.z,v1.w,
                   v2.x,v2.y,v2.z,v2.w, v3.x,v3.y,v3.z,v3.w};
    if ((0&3)==jq) As[r*LS + 0] = 0x3F80;
    #pragma unroll
    for (int q=0;q<16;q++) if (((1+q)&3)==jq) As[r*LS + 1+q] = f2bf(f[q]);
    int pos = 17;
    #pragma unroll
    for (int i=0;i<16;i++)
      #pragma unroll
      for (int j=i;j<16;j++){
        if ((pos&3)==jq) As[r*LS + pos] = f2bf(f[i]*f[j]*((i==j)?0.5f:RS2));
        pos++;
      }
    #pragma unroll
    for (int z=153;z<160;z++) if ((z&3)==jq) As[r*LS + z] = 0;
  }
  __syncthreads();
  f32x4 acc[5] = {};
  __builtin_amdgcn_s_setprio(1);
  #pragma unroll
  for (int ks=0;ks<5;ks++){
    int lk = ks*32 + ((lane>>4)<<3);
    bf16x8 a = *(const bf16x8*)(As + (wid*16 + (lane&15))*LS + lk);
    #pragma unroll
    for (int n=0;n<5;n++){
      bf16x8 bb = *(const bf16x8*)(Bs + (n*16 + (lane&15))*LS + lk);
      acc[n] = __builtin_amdgcn_mfma_f32_16x16x32_bf16(a, bb, acc[n], 0,0,0);
    }
  }
  __builtin_amdgcn_s_setprio(0);
  int rl = (lane>>4)<<2;
  #pragma unroll
  for (int r=0;r<4;r++){
    float nrm = __shfl(acc[4][r], lane & 48) + 1e-6f;
    float inv = 1.0f / nrm;
    int t = t0 + wid*16 + rl + r;
    #pragma unroll
    for (int n=0;n<4;n++){
      comb[(size_t)(b*TSEQ + t)*2048 + h*64 + n*16 + (lane&15)] = f2bf(acc[n][r]*inv);
    }
  }
}

// ---------------- sliding-window attention, 53.0KB LDS -> 3 blocks/CU ----------------
__global__ __launch_bounds__(256) void k_window(const u16* __restrict__ qwin,
    u16* __restrict__ comb){
  const int LQ = 72, LV = 136;
  __shared__ u16 k_s [128*LQ];
  __shared__ u16 vT  [64*LV];
  __shared__ u16 p_s [64*LV];
  int bh = blockIdx.x, b = bh>>4, h = bh&15;
  int t0 = blockIdx.y*64;
  int tid = threadIdx.x, lane = tid&63, wid = tid>>6;
  int j0 = t0 - 64;
  bf16x8 zv = {0,0,0,0,0,0,0,0};
  for (int cc=tid; cc<1024; cc+=256){
    int r = cc>>3, c8 = cc&7;
    int j = j0 + r;
    bf16x8 kv8 = (j>=0) ? *(const bf16x8*)(qwin + (size_t)(b*TSEQ + j)*3072 + 1024 + h*HD + c8*8) : zv;
    *(bf16x8*)(k_s + r*LQ + c8*8) = kv8;
    bf16x8 vv8 = (j>=0) ? *(const bf16x8*)(qwin + (size_t)(b*TSEQ + j)*3072 + 2048 + h*HD + c8*8) : zv;
    int cs = r ^ (c8<<3);
    #pragma unroll
    for (int e=0;e<8;e++) vT[(c8*8+e)*LV + cs] = (u16)vv8[e];
  }
  __syncthreads();
  f32x4 sa[8] = {};
  {
    const u16* qrow = qwin + (size_t)(b*TSEQ + t0 + wid*16 + (lane&15))*3072 + h*HD;
    __builtin_amdgcn_s_setprio(1);
    #pragma unroll
    for (int kk=0;kk<64;kk+=32){
      int lk = kk + ((lane>>4)<<3);
      bf16x8 a = *(const bf16x8*)(qrow + lk);
      #pragma unroll
      for (int n=0;n<8;n++){
        bf16x8 bb = *(const bf16x8*)(k_s + (n*16 + (lane&15))*LQ + lk);
        sa[n] = __builtin_amdgcn_mfma_f32_16x16x32_bf16(a, bb, sa[n], 0,0,0);
      }
    }
    __builtin_amdgcn_s_setprio(0);
  }
  int rl = (lane>>4)<<2;
  float pr[8][4];
  #pragma unroll
  for (int r=0;r<4;r++){
    int ig = t0 + wid*16 + rl + r;
    float mx = -1e30f;
    float sv[8];
    #pragma unroll
    for (int n=0;n<8;n++){
      int jg = j0 + n*16 + (lane&15);
      float s = sa[n][r]*0.125f;
      bool ok = (jg>=0) && (jg<=ig) && (jg>=ig-WIN);
      s = ok ? s : -1e30f;
      sv[n]=s; mx = fmaxf(mx, s);
    }
    #pragma unroll
    for (int m=1;m<16;m<<=1) mx = fmaxf(mx, __shfl_xor(mx, m));
    float sum = 0.f;
    #pragma unroll
    for (int n=0;n<8;n++){ float e = __expf(sv[n]-mx); sv[n]=e; sum += e; }
    #pragma unroll
    for (int m=1;m<16;m<<=1) sum += __shfl_xor(sum, m);
    float inv = 1.0f/sum;
    #pragma unroll
    for (int n=0;n<8;n++) pr[n][r] = sv[n]*inv;
  }
  #pragma unroll
  for (int n=0;n<8;n++)
    #pragma unroll
    for (int r=0;r<4;r++)
      p_s[(wid*16 + rl + r)*LV + n*16 + (lane&15)] = f2bf(pr[n][r]);
  __syncthreads();
  f32x4 oa[4] = {};
  __builtin_amdgcn_s_setprio(1);
  #pragma unroll
  for (int ks=0;ks<4;ks++){
    int lk = ks*32 + ((lane>>4)<<3);
    bf16x8 a = *(const bf16x8*)(p_s + (wid*16 + (lane&15))*LV + lk);
    #pragma unroll
    for (int n=0;n<4;n++){
      int d = n*16 + (lane&15);
      bf16x8 bb = *(const bf16x8*)(vT + d*LV + (lk ^ (((d>>3)&7)<<3)));
      oa[n] = __builtin_amdgcn_mfma_f32_16x16x32_bf16(a, bb, oa[n], 0,0,0);
    }
  }
  __builtin_amdgcn_s_setprio(0);
  #pragma unroll
  for (int n=0;n<4;n++)
    #pragma unroll
    for (int r=0;r<4;r++)
      comb[(size_t)(b*TSEQ + t0 + wid*16 + rl + r)*2048 + 1024 + h*HD + n*16 + (lane&15)]
        = f2bf(oa[n][r]);
}

extern "C" void kernel_launch(void* const* d_in, const int* in_sizes, int n_in,
                              void* d_out, int out_size, void* d_ws, size_t ws_size,
                              hipStream_t stream){
  (void)in_sizes; (void)n_in; (void)out_size; (void)ws_size;
  const float* x    = (const float*)d_in[0];
  const float* enc  = (const float*)d_in[1];
  const float* nw   = (const float*)d_in[2];
  const float* Wq   = (const float*)d_in[3];
  const float* Wkv  = (const float*)d_in[4];
  const float* Wqf  = (const float*)d_in[5];
  const float* Wkf  = (const float*)d_in[6];
  const float* Wwin = (const float*)d_in[7];
  const float* Wout = (const float*)d_in[8];
  float* out = (float*)d_out;

  char* p = (char*)d_ws;
  auto alloc = [&](size_t bytes)->char*{
    char* r = p; p += (bytes + 255) & ~(size_t)255; return r;
  };
  u16*   xn    = (u16*)  alloc((size_t)ROWS*DM*2);
  u16*   encb  = (u16*)  alloc((size_t)ROWS*DM*2);
  u16*   WqwT  = (u16*)  alloc((size_t)3072*DM*2);   // rows 0..1023 Wq^T, 1024..3071 Wwin^T
  u16*   WkvT2 = (u16*)  alloc((size_t)LDKV*DM*2);   // rows 0..1023 v-proj^T, 1024..1279 CmpT
  u16*   WoutT = (u16*)  alloc((size_t)DM*2048*2);
  u16*   WqfT  = (u16*)  alloc((size_t)FD*HD*2);
  u16*   qwin  = (u16*)  alloc((size_t)ROWS*3072*2); // [q | k_win | v_win], ld 3072
  u16*   kvb   = (u16*)  alloc((size_t)ROWS*LDKV*2); // [v | kf], ld 1280
  u16*   kvsT  = (u16*)  alloc((size_t)32*80*FPAD*2);
  u16*   comb  = (u16*)  alloc((size_t)ROWS*2048*2);
  u16*   part  = (u16*)  alloc((size_t)KSPLIT*32*80*FPAD*2);

  k_prep<<<2*ROWS + 6145 + 1024, 256, 0, stream>>>(x, enc, nw, Wq, Wwin, Wkv, Wout, Wqf, Wkf,
                                                   xn, encb, WqwT, WkvT2, WoutT, WqfT);

  k_gemm<0><<<dim3(ROWS/128, 34), 512, 0, stream>>>(
      xn, WqwT, qwin, 3072,  encb, WkvT2, kvb, LDKV,  24, DM, nullptr, nullptr);

  k_kvstate<<<dim3(32, KSPLIT), 256, 0, stream>>>(kvb, part);
  k_kvreduce<<<1600, 256, 0, stream>>>(part, kvsT);

  k_linattn<<<dim3(32, TSEQ/64), 256, 0, stream>>>(qwin, WqfT, kvsT, comb);
  k_window <<<dim3(32, TSEQ/64), 256, 0, stream>>>(qwin, comb);

  k_gemmN64<1><<<dim3(ROWS/128, 16), 512, 0, stream>>>(
      comb, WoutT, out, x, DM, 2048);
}

// Round 17
// 141.278 us; speedup vs baseline: 1.4343x; 1.0581x over previous
//
#include <hip/hip_runtime.h>

#define DM 1024
#define NH 16
#define HD 64
#define FD 16
#define NF 153
#define FPAD 160
#define WIN 64
#define TSEQ 2048
#define ROWS 4096
#define KSPLIT 32
#define LDKV 1280
#define RS2 0.70710678118654752f

typedef unsigned short u16;
typedef __attribute__((ext_vector_type(8))) short bf16x8;
typedef __attribute__((ext_vector_type(8))) unsigned short u16x8;
typedef __attribute__((ext_vector_type(4))) unsigned short u16x4;
typedef __attribute__((ext_vector_type(4))) float f32x4;

#define GLB_AS __attribute__((address_space(1)))
#define LDS_AS __attribute__((address_space(3)))

static __device__ __forceinline__ void gload_lds16(const void* g, void* l){
  __builtin_amdgcn_global_load_lds((const GLB_AS void*)g, (LDS_AS void*)l, 16, 0, 0);
}

static __device__ __forceinline__ float bf2f(u16 u){
  unsigned v = ((unsigned)u) << 16;
  return __builtin_bit_cast(float, v);
}
static __device__ __forceinline__ u16 f2bf(float f){
  unsigned u = __builtin_bit_cast(unsigned, f);
  u += 0x7FFFu + ((u >> 16) & 1u);
  return (u16)(u >> 16);
}

// ---------------- prep: rmsnorm + enc cast + weight packing + composed K-feature ----------------
static __device__ __forceinline__ void tr_tile(const float* __restrict__ in,
    u16* __restrict__ out, int K, int N, int n0, int k0, float* t, int tid){
  int tx = tid & 31, ty = tid >> 5;
  #pragma unroll
  for (int i=0;i<4;i++) t[(ty + i*8)*33 + tx] = in[(size_t)(k0 + ty + i*8)*N + n0 + tx];
  __syncthreads();
  #pragma unroll
  for (int i=0;i<4;i++) out[(size_t)(n0 + ty + i*8)*K + k0 + tx] = f2bf(t[tx*33 + ty + i*8]);
}

__global__ __launch_bounds__(256) void k_prep(const float* __restrict__ x,
    const float* __restrict__ enc, const float* __restrict__ w,
    const float* __restrict__ Wq, const float* __restrict__ Wwin,
    const float* __restrict__ Wkv, const float* __restrict__ Wout,
    const float* __restrict__ Wqf, const float* __restrict__ Wkf,
    u16* __restrict__ xn, u16* __restrict__ encb,
    u16* __restrict__ WqwT, u16* __restrict__ WkvT2, u16* __restrict__ WoutT,
    u16* __restrict__ WqfT){
  __shared__ float t[32*33];
  __shared__ float wkf[1024];
  __shared__ float wkv[1024];
  int bx = blockIdx.x, tid = threadIdx.x;
  if (bx < ROWS){
    int row = bx;
    const float4* xr = (const float4*)(x + (size_t)row*DM);
    float4 a = xr[tid];
    float ss = a.x*a.x + a.y*a.y + a.z*a.z + a.w*a.w;
    #pragma unroll
    for (int m=1;m<64;m<<=1) ss += __shfl_xor(ss, m);
    __shared__ float red[4];
    if ((tid&63)==0) red[tid>>6] = ss;
    __syncthreads();
    float tot = red[0]+red[1]+red[2]+red[3];
    float rs = rsqrtf(tot*(1.0f/DM) + 1e-6f);
    float4 wv = ((const float4*)w)[tid];
    u16x4 o;
    o[0]=f2bf(a.x*rs*wv.x); o[1]=f2bf(a.y*rs*wv.y);
    o[2]=f2bf(a.z*rs*wv.z); o[3]=f2bf(a.w*rs*wv.w);
    ((u16x4*)(xn + (size_t)row*DM))[tid] = o;
  } else if (bx < 2*ROWS){
    int row = bx - ROWS;
    float4 a = ((const float4*)(enc + (size_t)row*DM))[tid];
    u16x4 o;
    o[0]=f2bf(a.x); o[1]=f2bf(a.y); o[2]=f2bf(a.z); o[3]=f2bf(a.w);
    ((u16x4*)(encb + (size_t)row*DM))[tid] = o;
  } else {
    int b = bx - 2*ROWS;
    if (b < 1024){
      tr_tile(Wq, WqwT, 1024, 1024, (b&31)*32, (b>>5)*32, t, tid);
    } else if (b < 3072){
      int r = b-1024;
      tr_tile(Wwin, WqwT + (size_t)1024*1024, 1024, 2048, (r&63)*32, (r>>6)*32, t, tid);
    } else if (b < 4096){
      int r = b-3072;   // v-part: WkvT2 rows 0..1023 = Wkv cols 1024..2047 transposed
      tr_tile(Wkv + 1024, WkvT2, 1024, 2048, (r&31)*32, (r>>5)*32, t, tid);
    } else if (b < 6144){
      int r = b-4096;
      tr_tile(Wout, WoutT, 2048, 1024, (r&31)*32, (r>>5)*32, t, tid);
    } else if (b == 6144){
      for (int i=tid;i<1024;i+=256) WqfT[i] = f2bf(Wqf[(i&63)*16 + (i>>6)]);
    } else {
      // composed K-feature, parallel over 1024 blocks (h, din-chunk of 16)
      int idx = b - 6145;
      int h = idx >> 6, dc = idx & 63;
      for (int i=tid;i<1024;i+=256) wkf[i] = Wkf[i];
      {
        int rr = tid>>6, cc = tid&63;
        #pragma unroll
        for (int r2=0;r2<4;r2++)
          wkv[(rr + r2*4)*64 + cc] = Wkv[(size_t)(dc*16 + rr + r2*4)*2048 + h*64 + cc];
      }
      __syncthreads();
      int f = tid&15, dl = tid>>4;
      float acc = 0.f;
      #pragma unroll
      for (int d=0;d<64;d++) acc += wkv[dl*64 + d]*wkf[d*16 + f];
      WkvT2[(size_t)(1024 + h*16 + f)*1024 + dc*16 + dl] = f2bf(acc);
    }
  }
}

// ---------------- batched pipelined GEMM: 512 threads, 8 waves, wave tile 64x32 ----------------
template<int EPI>
__global__ __launch_bounds__(512) void k_gemm(
    const u16* __restrict__ A0, const u16* __restrict__ B0, u16* __restrict__ C0, int ldc0,
    const u16* __restrict__ A1, const u16* __restrict__ B1, u16* __restrict__ C1, int ldc1,
    int split, int K, float* __restrict__ Cf, const float* __restrict__ resid){
  __shared__ u16 As0[128*64];
  __shared__ u16 Bs0[128*64];
  __shared__ u16 As1[128*64];
  __shared__ u16 Bs1[128*64];
  int by = blockIdx.y;
  const u16 *A, *Bt; u16* C; int ldc;
  if (by < split){ A=A0; Bt=B0; C=C0; ldc=ldc0; }
  else { by -= split; A=A1; Bt=B1; C=C1; ldc=ldc1; }
  int row0 = blockIdx.x*128, col0 = by*128;
  int tid = threadIdx.x, lane = tid&63, wid = tid>>6;
  int wm = wid>>2, wn = wid&3;
  int srow = lane>>3;
  int scb  = ((lane&7)*16) ^ (srow<<4);
  f32x4 acc[4][2] = {};

  auto STAGE = [&](u16* Asb, u16* Bsb, int k0){
    #pragma unroll
    for (int i=0;i<2;i++){
      int chunk = wid*2 + i;
      int r = chunk*8 + srow;
      gload_lds16((const char*)(A  + (size_t)(row0+r)*K + k0) + scb, (char*)Asb + chunk*1024);
      gload_lds16((const char*)(Bt + (size_t)(col0+r)*K + k0) + scb, (char*)Bsb + chunk*1024);
    }
  };
  auto COMPUTE = [&](const u16* Asb, const u16* Bsb){
    #pragma unroll
    for (int kk=0;kk<64;kk+=32){
      int bc = 2*(kk + ((lane>>4)<<3));
      bf16x8 af[4], bfm[2];
      #pragma unroll
      for (int m=0;m<4;m++){
        int r = wm*64 + m*16 + (lane&15);
        af[m]  = *(const bf16x8*)((const char*)Asb + r*128 + (bc ^ ((r&7)<<4)));
      }
      #pragma unroll
      for (int n=0;n<2;n++){
        int r = wn*32 + n*16 + (lane&15);
        bfm[n] = *(const bf16x8*)((const char*)Bsb + r*128 + (bc ^ ((r&7)<<4)));
      }
      #pragma unroll
      for (int m=0;m<4;m++)
        #pragma unroll
        for (int n=0;n<2;n++)
          acc[m][n] = __builtin_amdgcn_mfma_f32_16x16x32_bf16(af[m], bfm[n], acc[m][n], 0,0,0);
    }
  };

  int nt = K >> 6;
  STAGE(As0, Bs0, 0);
  for (int t=0; t<nt-2; t+=2){
    STAGE(As1, Bs1, (t+1)*64);
    asm volatile("s_waitcnt vmcnt(4)" ::: "memory");
    __builtin_amdgcn_s_barrier();
    COMPUTE(As0, Bs0);
    __builtin_amdgcn_s_barrier();
    STAGE(As0, Bs0, (t+2)*64);
    asm volatile("s_waitcnt vmcnt(4)" ::: "memory");
    __builtin_amdgcn_s_barrier();
    COMPUTE(As1, Bs1);
    __builtin_amdgcn_s_barrier();
  }
  STAGE(As1, Bs1, (nt-1)*64);
  asm volatile("s_waitcnt vmcnt(4)" ::: "memory");
  __builtin_amdgcn_s_barrier();
  COMPUTE(As0, Bs0);
  asm volatile("s_waitcnt vmcnt(0)" ::: "memory");
  __builtin_amdgcn_s_barrier();
  COMPUTE(As1, Bs1);

  int rl = (lane>>4)<<2;
  #pragma unroll
  for (int m=0;m<4;m++){
    #pragma unroll
    for (int n=0;n<2;n++){
      int gc = col0 + wn*32 + n*16 + (lane&15);
      #pragma unroll
      for (int r=0;r<4;r++){
        size_t gi = (size_t)(row0 + wm*64 + m*16 + rl + r)*ldc + gc;
        if constexpr (EPI) Cf[gi] = acc[m][n][r] + resid[gi];
        else               C[gi]  = f2bf(acc[m][n][r]);
      }
    }
  }
}

// ---------------- Wout GEMM: 128x64 tiles, 512 thr / 8 waves, 48KB LDS ----------------
template<int EPI>
__global__ __launch_bounds__(512) void k_gemmN64(const u16* __restrict__ A,
    const u16* __restrict__ Bt, float* __restrict__ Cf,
    const float* __restrict__ resid, int ldc, int K){
  __shared__ u16 As0[128*64];
  __shared__ u16 Bs0[64*64];
  __shared__ u16 As1[128*64];
  __shared__ u16 Bs1[64*64];
  int row0 = blockIdx.x*128, col0 = blockIdx.y*64;
  int tid = threadIdx.x, lane = tid&63, wid = tid>>6;
  int wm = wid>>1, wn = wid&1;
  int srow = lane>>3;
  int scb  = ((lane&7)*16) ^ (srow<<4);
  f32x4 acc[2][2] = {};

  auto STAGE = [&](u16* Asb, u16* Bsb, int k0){
    #pragma unroll
    for (int j=0;j<2;j++){
      int c = wid*2 + j;
      int r = c*8 + srow;
      gload_lds16((const char*)(A + (size_t)(row0+r)*K + k0) + scb, (char*)Asb + c*1024);
    }
    {
      int c = wid;
      int r = c*8 + srow;
      gload_lds16((const char*)(Bt + (size_t)(col0+r)*K + k0) + scb, (char*)Bsb + c*1024);
    }
  };
  auto COMPUTE = [&](const u16* Asb, const u16* Bsb){
    #pragma unroll
    for (int kk=0;kk<64;kk+=32){
      int bc = 2*(kk + ((lane>>4)<<3));
      bf16x8 af[2], bfm[2];
      #pragma unroll
      for (int m=0;m<2;m++){
        int r = wm*32 + m*16 + (lane&15);
        af[m]  = *(const bf16x8*)((const char*)Asb + r*128 + (bc ^ ((r&7)<<4)));
      }
      #pragma unroll
      for (int n=0;n<2;n++){
        int r = wn*32 + n*16 + (lane&15);
        bfm[n] = *(const bf16x8*)((const char*)Bsb + r*128 + (bc ^ ((r&7)<<4)));
      }
      #pragma unroll
      for (int m=0;m<2;m++)
        #pragma unroll
        for (int n=0;n<2;n++)
          acc[m][n] = __builtin_amdgcn_mfma_f32_16x16x32_bf16(af[m], bfm[n], acc[m][n], 0,0,0);
    }
  };

  int nt = K >> 6;
  STAGE(As0, Bs0, 0);
  for (int t=0; t<nt-2; t+=2){
    STAGE(As1, Bs1, (t+1)*64);
    asm volatile("s_waitcnt vmcnt(3)" ::: "memory");
    __builtin_amdgcn_s_barrier();
    COMPUTE(As0, Bs0);
    __builtin_amdgcn_s_barrier();
    STAGE(As0, Bs0, (t+2)*64);
    asm volatile("s_waitcnt vmcnt(3)" ::: "memory");
    __builtin_amdgcn_s_barrier();
    COMPUTE(As1, Bs1);
    __builtin_amdgcn_s_barrier();
  }
  STAGE(As1, Bs1, (nt-1)*64);
  asm volatile("s_waitcnt vmcnt(3)" ::: "memory");
  __builtin_amdgcn_s_barrier();
  COMPUTE(As0, Bs0);
  asm volatile("s_waitcnt vmcnt(0)" ::: "memory");
  __builtin_amdgcn_s_barrier();
  COMPUTE(As1, Bs1);

  int rl = (lane>>4)<<2;
  #pragma unroll
  for (int m=0;m<2;m++){
    #pragma unroll
    for (int n=0;n<2;n++){
      int gc = col0 + wn*32 + n*16 + (lane&15);
      #pragma unroll
      for (int r=0;r<4;r++){
        size_t gi = (size_t)(row0 + wm*32 + m*16 + rl + r)*ldc + gc;
        if constexpr (EPI) Cf[gi] = acc[m][n][r] + resid[gi];
        else               ((u16*)Cf)[gi] = f2bf(acc[m][n][r]);
      }
    }
  }
}

// ---------------- kv_state: kf precomputed in kvb -> single-barrier structure ----------------
__global__ __launch_bounds__(256) void k_kvstate(const u16* __restrict__ kvb,
    u16* __restrict__ part){
  const int P = 72;
  __shared__ u16 ph[160*P];
  __shared__ u16 vt[80*P];
  int bh = blockIdx.x, b = bh>>4, h = bh&15;
  int ks = blockIdx.y;
  int tid = threadIdx.x, lane = tid&63, w = tid>>6;
  int s0 = ks*64;
  for (int i=tid; i<16*P; i+=256){
    int r = 64 + i/P, c = i - (i/P)*P;
    vt[r*P + c] = (r==64) ? (u16)0x3F80 : (u16)0;
  }
  for (int s = w; s < 64; s += 4)
    vt[lane*P + s] = kvb[(size_t)(b*TSEQ + s0 + s)*LDKV + h*HD + lane];
  {
    int r = tid>>2, jq = tid&3;
    const u16* kfp = kvb + (size_t)(b*TSEQ + s0 + r)*LDKV + 1024 + h*16;
    u16x8 va = *(const u16x8*)kfp;
    u16x8 vb = *(const u16x8*)(kfp + 8);
    float f[16];
    #pragma unroll
    for (int j=0;j<8;j++){ f[j] = bf2f(va[j]); f[8+j] = bf2f(vb[j]); }
    if ((0&3)==jq) ph[0*P + r] = 0x3F80;
    #pragma unroll
    for (int q=0;q<16;q++) if (((1+q)&3)==jq) ph[(1+q)*P + r] = f2bf(f[q]);
    int pos = 17;
    #pragma unroll
    for (int i=0;i<16;i++)
      #pragma unroll
      for (int j=i;j<16;j++){
        if ((pos&3)==jq) ph[pos*P + r] = f2bf(f[i]*f[j]*((i==j)?0.5f:RS2));
        pos++;
      }
    #pragma unroll
    for (int z=153;z<160;z++) if ((z&3)==jq) ph[z*P + r] = 0;
  }
  __syncthreads();
  f32x4 acc[5][3] = {};
  #pragma unroll
  for (int kk=0;kk<2;kk++){
    int lk = kk*32 + ((lane>>4)<<3);
    bf16x8 bfr[3];
    #pragma unroll
    for (int nn=0;nn<3;nn++){
      int ncol = (nn<2) ? (w*2+nn) : (8+(w&1));
      bfr[nn] = *(const bf16x8*)(ph + (ncol*16 + (lane&15))*P + lk);
    }
    #pragma unroll
    for (int m=0;m<5;m++){
      bf16x8 av = *(const bf16x8*)(vt + (m*16 + (lane&15))*P + lk);
      #pragma unroll
      for (int nn=0;nn<3;nn++)
        acc[m][nn] = __builtin_amdgcn_mfma_f32_16x16x32_bf16(av, bfr[nn], acc[m][nn], 0,0,0);
    }
  }
  int rl = (lane>>4)<<2;
  u16* pp = part + ((size_t)ks*32 + bh)*80*160;
  #pragma unroll
  for (int m=0;m<5;m++){
    #pragma unroll
    for (int nn=0;nn<3;nn++){
      int ncol = (nn<2) ? (w*2+nn) : (8+(w&1));
      if (nn==2 && w>=2) continue;
      int fcol = ncol*16 + (lane&15);
      #pragma unroll
      for (int r=0;r<4;r++)
        pp[(size_t)(m*16 + rl + r)*160 + fcol] = f2bf(acc[m][nn][r]);
    }
  }
}

// ---------------- reduce split-K bf16 partials -> kvsT bf16 [bh][80][160] ----------------
__global__ __launch_bounds__(256) void k_kvreduce(const u16* __restrict__ part,
    u16* __restrict__ kvsT){
  int i = blockIdx.x*256 + threadIdx.x;
  float s = 0.f;
  #pragma unroll
  for (int c=0;c<KSPLIT;c++) s += bf2f(part[(size_t)c*409600 + i]);
  kvsT[i] = f2bf(s);
}

// ---------------- MERGED attention dispatch: by<32 -> linattn tile, else window tile ----------------
// NOT phase-fusion (R7 lesson): each block runs exactly ONE of the two independent
// workloads; merging only interleaves them across CUs and drops a dispatch ramp.
// LDS union arena = 53248 B -> 3 blocks/CU for both variants.
__global__ __launch_bounds__(256) void k_attn(const u16* __restrict__ qwin,
    const u16* __restrict__ WqfT, const u16* __restrict__ kvsT, u16* __restrict__ comb){
  __shared__ u16 arena[26624];
  int bh = blockIdx.x, b = bh>>4, h = bh&15;
  int tid = threadIdx.x, lane = tid&63, wid = tid>>6;
  int rl = (lane>>4)<<2;

  if (blockIdx.y < 32){
    // ================= linear attention =================
    const int LS = 168;
    float* fL = (float*)arena;          // 4096 B
    u16*   As = arena + 2048;           // 64*168*2 = 21504 B
    u16*   Bs = arena + 2048 + 10752;   // 80*168*2 = 26880 B  (total 52480)
    int t0 = blockIdx.y*64;
    for (int i=tid*8; i<80*FPAD; i+=2048){
      int r = i/FPAD, ff = i - r*FPAD;
      *(bf16x8*)(Bs + r*LS + ff) = *(const bf16x8*)(kvsT + (size_t)bh*80*FPAD + i);
    }
    {
      f32x4 fa = {};
      const u16* qrow = qwin + (size_t)(b*TSEQ + t0 + wid*16 + (lane&15))*3072 + h*HD;
      const u16* wrow = WqfT + (lane&15)*64;
      #pragma unroll
      for (int kk=0;kk<2;kk++){
        int ko = kk*32 + ((lane>>4)<<3);
        bf16x8 av = *(const bf16x8*)(qrow + ko);
        bf16x8 bv = *(const bf16x8*)(wrow + ko);
        fa = __builtin_amdgcn_mfma_f32_16x16x32_bf16(av, bv, fa, 0,0,0);
      }
      #pragma unroll
      for (int r=0;r<4;r++) fL[(wid*16 + rl + r)*16 + (lane&15)] = fa[r];
    }
    __syncthreads();
    {
      int r = tid>>2, jq = tid&3;
      float4 v0 = *(const float4*)(fL + r*16 + 0);
      float4 v1 = *(const float4*)(fL + r*16 + 4);
      float4 v2 = *(const float4*)(fL + r*16 + 8);
      float4 v3 = *(const float4*)(fL + r*16 + 12);
      float f[16] = {v0.x,v0.y,v0.z,v0.w, v1.x,v1.y,v1.z,v1.w,
                     v2.x,v2.y,v2.z,v2.w, v3.x,v3.y,v3.z,v3.w};
      if ((0&3)==jq) As[r*LS + 0] = 0x3F80;
      #pragma unroll
      for (int q=0;q<16;q++) if (((1+q)&3)==jq) As[r*LS + 1+q] = f2bf(f[q]);
      int pos = 17;
      #pragma unroll
      for (int i=0;i<16;i++)
        #pragma unroll
        for (int j=i;j<16;j++){
          if ((pos&3)==jq) As[r*LS + pos] = f2bf(f[i]*f[j]*((i==j)?0.5f:RS2));
          pos++;
        }
      #pragma unroll
      for (int z=153;z<160;z++) if ((z&3)==jq) As[r*LS + z] = 0;
    }
    __syncthreads();
    f32x4 acc[5] = {};
    __builtin_amdgcn_s_setprio(1);
    #pragma unroll
    for (int ks=0;ks<5;ks++){
      int lk = ks*32 + ((lane>>4)<<3);
      bf16x8 a = *(const bf16x8*)(As + (wid*16 + (lane&15))*LS + lk);
      #pragma unroll
      for (int n=0;n<5;n++){
        bf16x8 bb = *(const bf16x8*)(Bs + (n*16 + (lane&15))*LS + lk);
        acc[n] = __builtin_amdgcn_mfma_f32_16x16x32_bf16(a, bb, acc[n], 0,0,0);
      }
    }
    __builtin_amdgcn_s_setprio(0);
    #pragma unroll
    for (int r=0;r<4;r++){
      float nrm = __shfl(acc[4][r], lane & 48) + 1e-6f;
      float inv = 1.0f / nrm;
      int t = t0 + wid*16 + rl + r;
      #pragma unroll
      for (int n=0;n<4;n++){
        comb[(size_t)(b*TSEQ + t)*2048 + h*64 + n*16 + (lane&15)] = f2bf(acc[n][r]*inv);
      }
    }
  } else {
    // ================= sliding-window attention =================
    const int LQ = 72, LV = 136;
    u16* k_s = arena;                 // 128*72*2 = 18432 B
    u16* vT  = arena + 9216;          // 64*136*2 = 17408 B
    u16* p_s = arena + 17920;         // 64*136*2 = 17408 B (total 53248)
    int t0 = (blockIdx.y - 32)*64;
    int j0 = t0 - 64;
    bf16x8 zv = {0,0,0,0,0,0,0,0};
    for (int cc=tid; cc<1024; cc+=256){
      int r = cc>>3, c8 = cc&7;
      int j = j0 + r;
      bf16x8 kv8 = (j>=0) ? *(const bf16x8*)(qwin + (size_t)(b*TSEQ + j)*3072 + 1024 + h*HD + c8*8) : zv;
      *(bf16x8*)(k_s + r*LQ + c8*8) = kv8;
      bf16x8 vv8 = (j>=0) ? *(const bf16x8*)(qwin + (size_t)(b*TSEQ + j)*3072 + 2048 + h*HD + c8*8) : zv;
      int cs = r ^ (c8<<3);
      #pragma unroll
      for (int e=0;e<8;e++) vT[(c8*8+e)*LV + cs] = (u16)vv8[e];
    }
    __syncthreads();
    f32x4 sa[8] = {};
    {
      const u16* qrow = qwin + (size_t)(b*TSEQ + t0 + wid*16 + (lane&15))*3072 + h*HD;
      __builtin_amdgcn_s_setprio(1);
      #pragma unroll
      for (int kk=0;kk<64;kk+=32){
        int lk = kk + ((lane>>4)<<3);
        bf16x8 a = *(const bf16x8*)(qrow + lk);
        #pragma unroll
        for (int n=0;n<8;n++){
          bf16x8 bb = *(const bf16x8*)(k_s + (n*16 + (lane&15))*LQ + lk);
          sa[n] = __builtin_amdgcn_mfma_f32_16x16x32_bf16(a, bb, sa[n], 0,0,0);
        }
      }
      __builtin_amdgcn_s_setprio(0);
    }
    float pr[8][4];
    #pragma unroll
    for (int r=0;r<4;r++){
      int ig = t0 + wid*16 + rl + r;
      float mx = -1e30f;
      float sv[8];
      #pragma unroll
      for (int n=0;n<8;n++){
        int jg = j0 + n*16 + (lane&15);
        float s = sa[n][r]*0.125f;
        bool ok = (jg>=0) && (jg<=ig) && (jg>=ig-WIN);
        s = ok ? s : -1e30f;
        sv[n]=s; mx = fmaxf(mx, s);
      }
      #pragma unroll
      for (int m=1;m<16;m<<=1) mx = fmaxf(mx, __shfl_xor(mx, m));
      float sum = 0.f;
      #pragma unroll
      for (int n=0;n<8;n++){ float e = __expf(sv[n]-mx); sv[n]=e; sum += e; }
      #pragma unroll
      for (int m=1;m<16;m<<=1) sum += __shfl_xor(sum, m);
      float inv = 1.0f/sum;
      #pragma unroll
      for (int n=0;n<8;n++) pr[n][r] = sv[n]*inv;
    }
    #pragma unroll
    for (int n=0;n<8;n++)
      #pragma unroll
      for (int r=0;r<4;r++)
        p_s[(wid*16 + rl + r)*LV + n*16 + (lane&15)] = f2bf(pr[n][r]);
    __syncthreads();
    f32x4 oa[4] = {};
    __builtin_amdgcn_s_setprio(1);
    #pragma unroll
    for (int ks=0;ks<4;ks++){
      int lk = ks*32 + ((lane>>4)<<3);
      bf16x8 a = *(const bf16x8*)(p_s + (wid*16 + (lane&15))*LV + lk);
      #pragma unroll
      for (int n=0;n<4;n++){
        int d = n*16 + (lane&15);
        bf16x8 bb = *(const bf16x8*)(vT + d*LV + (lk ^ (((d>>3)&7)<<3)));
        oa[n] = __builtin_amdgcn_mfma_f32_16x16x32_bf16(a, bb, oa[n], 0,0,0);
      }
    }
    __builtin_amdgcn_s_setprio(0);
    #pragma unroll
    for (int n=0;n<4;n++)
      #pragma unroll
      for (int r=0;r<4;r++)
        comb[(size_t)(b*TSEQ + t0 + wid*16 + rl + r)*2048 + 1024 + h*HD + n*16 + (lane&15)]
          = f2bf(oa[n][r]);
  }
}

extern "C" void kernel_launch(void* const* d_in, const int* in_sizes, int n_in,
                              void* d_out, int out_size, void* d_ws, size_t ws_size,
                              hipStream_t stream){
  (void)in_sizes; (void)n_in; (void)out_size; (void)ws_size;
  const float* x    = (const float*)d_in[0];
  const float* enc  = (const float*)d_in[1];
  const float* nw   = (const float*)d_in[2];
  const float* Wq   = (const float*)d_in[3];
  const float* Wkv  = (const float*)d_in[4];
  const float* Wqf  = (const float*)d_in[5];
  const float* Wkf  = (const float*)d_in[6];
  const float* Wwin = (const float*)d_in[7];
  const float* Wout = (const float*)d_in[8];
  float* out = (float*)d_out;

  char* p = (char*)d_ws;
  auto alloc = [&](size_t bytes)->char*{
    char* r = p; p += (bytes + 255) & ~(size_t)255; return r;
  };
  u16*   xn    = (u16*)  alloc((size_t)ROWS*DM*2);
  u16*   encb  = (u16*)  alloc((size_t)ROWS*DM*2);
  u16*   WqwT  = (u16*)  alloc((size_t)3072*DM*2);   // rows 0..1023 Wq^T, 1024..3071 Wwin^T
  u16*   WkvT2 = (u16*)  alloc((size_t)LDKV*DM*2);   // rows 0..1023 v-proj^T, 1024..1279 CmpT
  u16*   WoutT = (u16*)  alloc((size_t)DM*2048*2);
  u16*   WqfT  = (u16*)  alloc((size_t)FD*HD*2);
  u16*   qwin  = (u16*)  alloc((size_t)ROWS*3072*2); // [q | k_win | v_win], ld 3072
  u16*   kvb   = (u16*)  alloc((size_t)ROWS*LDKV*2); // [v | kf], ld 1280
  u16*   kvsT  = (u16*)  alloc((size_t)32*80*FPAD*2);
  u16*   comb  = (u16*)  alloc((size_t)ROWS*2048*2);
  u16*   part  = (u16*)  alloc((size_t)KSPLIT*32*80*FPAD*2);

  k_prep<<<2*ROWS + 6145 + 1024, 256, 0, stream>>>(x, enc, nw, Wq, Wwin, Wkv, Wout, Wqf, Wkf,
                                                   xn, encb, WqwT, WkvT2, WoutT, WqfT);

  k_gemm<0><<<dim3(ROWS/128, 34), 512, 0, stream>>>(
      xn, WqwT, qwin, 3072,  encb, WkvT2, kvb, LDKV,  24, DM, nullptr, nullptr);

  k_kvstate<<<dim3(32, KSPLIT), 256, 0, stream>>>(kvb, part);
  k_kvreduce<<<1600, 256, 0, stream>>>(part, kvsT);

  k_attn<<<dim3(32, 64), 256, 0, stream>>>(qwin, WqfT, kvsT, comb);

  k_gemmN64<1><<<dim3(ROWS/128, 16), 512, 0, stream>>>(
      comb, WoutT, out, x, DM, 2048);
}